// Round 8
// baseline (141.120 us; speedup 1.0000x reference)
//
#include <hip/hip_runtime.h>
#include <math.h>

#define KS 11
#define CHUNK 44      // output rows per block = 4 x 11 (ring phases static)
#define GRIDY 12      // 12*44 = 528 >= 512; tail rows masked out of the sum
#define IMW 512
#define IMH 512

struct G11 { float g[KS]; };

typedef int   v4i __attribute__((ext_vector_type(4)));
typedef float f2  __attribute__((ext_vector_type(2)));

// CK-style direct binding to the raw buffer load intrinsic: compiler tracks
// the load (auto waitcnt), folds constant voffset adds into the 12-bit imm.
__device__ float
raw_buf_load_f32(v4i srsrc, int voffset, int soffset, int aux)
    __asm("llvm.amdgcn.raw.buffer.load.f32");

// SRD over ONE image row: num_records = IMW*4 bytes, stride 0.
// OOB lanes (voffset < 0 treated as huge unsigned, or >= IMW*4) return 0 —
// exactly the reference conv's zero-padding, at zero VALU cost.
__device__ inline v4i make_row_srd(const float* row) {
    union { const float* p; unsigned u[2]; } a; a.p = row;
    v4i r;
    r.x = (int)a.u[0];
    r.y = (int)a.u[1];
    r.z = IMW * 4;          // num_records (bytes, stride==0)
    r.w = 0x00020000;       // raw untyped dword access
    return r;
}

// Each thread owns one output column x and streams CHUNK rows downward.
// pred/target are packed as {p,t} float2 lanes so the twin conv chains
// compile to packed fp32 (v_pk_*). 11-deep register ring of the
// horizontal-conv quantities; every ring index is compile-time constant.
// __launch_bounds__(256,5): pin VGPR<=102 -> 5 waves/SIMD; grid of 1152
// blocks (4.5/CU) is then FULLY resident in a single wave-up.
__global__ __launch_bounds__(256, 5) void ssim_col_kernel(
    const float* __restrict__ pred, const float* __restrict__ target,
    float* __restrict__ partial, G11 gw)
{
    const int tid = threadIdx.x;
    const int x   = blockIdx.x * 256 + tid;       // output column, 0..511
    const int y0  = blockIdx.y * CHUNK;           // first output row
    const int bc  = blockIdx.z;
    const float* pimg = pred   + (size_t)bc * (IMH * IMW);
    const float* timg = target + (size_t)bc * (IMH * IMW);

    // single per-lane byte offset of the leftmost tap (may be negative: OOB->0)
    const int vx = (x - 5) * 4;

    // ring: hA = {mu1-acc, mu2-acc}, hB = {E[p^2]-acc, E[t^2]-acc}, hc = E[pt]-acc
    f2    hA[KS], hB[KS];
    float hc[KS];

    // Ingest input row YI into ring slot S (S compile-time constant).
#define INGEST(S, YI)                                                       \
    {                                                                       \
        const int yi = (YI);                                                \
        f2 A = {0.f, 0.f}, Bq = {0.f, 0.f};                                 \
        float c4 = 0.f;                                                     \
        if ((unsigned)yi < (unsigned)IMH) {                                 \
            const v4i ps = make_row_srd(pimg + (size_t)yi * IMW);           \
            const v4i ts = make_row_srd(timg + (size_t)yi * IMW);           \
            f2 pt[KS];                                                      \
            _Pragma("unroll")                                               \
            for (int j = 0; j < KS; ++j) {                                  \
                pt[j].x = raw_buf_load_f32(ps, vx + 4 * j, 0, 0);           \
                pt[j].y = raw_buf_load_f32(ts, vx + 4 * j, 0, 0);           \
            }                                                               \
            _Pragma("unroll")                                               \
            for (int j = 0; j < KS; ++j) {                                  \
                const f2 w2 = {gw.g[j], gw.g[j]};                           \
                const f2 wv = w2 * pt[j];          /* {w p, w t} */         \
                A  = A + wv;                                                \
                Bq = __builtin_elementwise_fma(wv, pt[j], Bq);              \
                c4 = fmaf(wv.x, pt[j].y, c4);      /* w p t */              \
            }                                                               \
        }                                                                   \
        hA[S] = A; hB[S] = Bq; hc[S] = c4;                                  \
    }

    // Prologue: fill slots 0..9 with input rows y0-5 .. y0+4.
    #pragma unroll
    for (int i = 0; i < 10; ++i) {
        INGEST(i, y0 - 5 + i)
    }

    const float C1 = 1e-4f, C2 = 9e-4f;
    float acc = 0.f;

    // Main: output row y = y0+k0+kk; ingest input row y+5 into slot
    // (kk+10)%11; vertical tap j reads slot (kk+j)%11. k0 is a multiple
    // of 11, so all slots depend only on kk (compile-time).
    for (int k0 = 0; k0 < CHUNK; k0 += KS) {
        #pragma unroll
        for (int kk = 0; kk < KS; ++kk) {
            const int k = k0 + kk;
            INGEST((kk + 10) % KS, y0 + k + 5)

            f2 M = {0.f, 0.f}, S2 = {0.f, 0.f};
            float s12 = 0.f;
            #pragma unroll
            for (int j = 0; j < KS; ++j) {
                const f2 w2 = {gw.g[j], gw.g[j]};
                M   = __builtin_elementwise_fma(w2, hA[(kk + j) % KS], M);
                S2  = __builtin_elementwise_fma(w2, hB[(kk + j) % KS], S2);
                s12 = fmaf(gw.g[j], hc[(kk + j) % KS], s12);
            }
            const float m1 = M.x, m2 = M.y;
            const float mu1s = m1 * m1, mu2s = m2 * m2, mu12 = m1 * m2;
            const float sg1  = S2.x - mu1s;
            const float sg2  = S2.y - mu2s;
            const float sg12 = s12 - mu12;
            const float num = (2.f * mu12 + C1) * (2.f * sg12 + C2);
            const float den = (mu1s + mu2s + C1) * (sg1 + sg2 + C2);
            const float val = num * __builtin_amdgcn_rcpf(den);
            // mask output rows beyond the image (block y=11 covers 484..527)
            acc += (y0 + k < IMH) ? val : 0.f;
        }
    }
#undef INGEST

    // Block reduction: wave shfl, then cross-wave via tiny LDS.
    __shared__ float wsum[4];
    #pragma unroll
    for (int off = 32; off > 0; off >>= 1) acc += __shfl_down(acc, off, 64);
    const int wid = tid >> 6, lane = tid & 63;
    if (lane == 0) wsum[wid] = acc;
    __syncthreads();
    if (tid == 0) {
        atomicAdd(partial, wsum[0] + wsum[1] + wsum[2] + wsum[3]);
    }
}

__global__ void ssim_final_kernel(const float* __restrict__ partial,
                                  float* __restrict__ out, float invN)
{
    out[0] = 1.f - partial[0] * invN;
}

extern "C" void kernel_launch(void* const* d_in, const int* in_sizes, int n_in,
                              void* d_out, int out_size, void* d_ws, size_t ws_size,
                              hipStream_t stream) {
    const float* pred   = (const float*)d_in[0];
    const float* target = (const float*)d_in[1];
    float* out = (float*)d_out;
    float* partial = (float*)d_ws;

    const int B = 16, C = 3;
    const float invN = 1.0f / ((float)B * C * IMH * IMW);

    // separable 1-D Gaussian, same formula as reference (sigma=1.5, 11 taps)
    G11 gw;
    {
        float s = 0.f;
        for (int i = 0; i < KS; ++i) {
            double e = exp(-((double)((i - 5) * (i - 5))) / (2.0 * 1.5 * 1.5));
            gw.g[i] = (float)e;
            s += gw.g[i];
        }
        for (int i = 0; i < KS; ++i) gw.g[i] /= s;
    }

    hipMemsetAsync(partial, 0, sizeof(float), stream);

    dim3 grid(IMW / 256, GRIDY, B * C);   // 2 x 12 x 48 = 1152 blocks
    dim3 block(256);
    ssim_col_kernel<<<grid, block, 0, stream>>>(pred, target, partial, gw);
    ssim_final_kernel<<<1, 1, 0, stream>>>(partial, out, invN);
}